// Round 4
// baseline (214.183 us; speedup 1.0000x reference)
//
#include <hip/hip_runtime.h>
#include <hip/hip_bf16.h>

#define Bb 512
#define Tt 512
#define Kk 64
#define START_TAG 62
#define STOP_TAG 63
#define LN2F 0.69314718055994530942f
#define LOG2E 1.44269504088896340736f

typedef __attribute__((ext_vector_type(8))) short bf16x8;  // 8 bf16 in 4 VGPRs
typedef __attribute__((ext_vector_type(4))) float f32x4;   // MFMA C/D

__device__ inline short f2bf(float x) {
    __hip_bfloat16 h = __float2bfloat16(x);
    short s; __builtin_memcpy(&s, &h, 2); return s;
}
__device__ inline float bperm(int addr_bytes, float v) {
    return __int_as_float(__builtin_amdgcn_ds_bpermute(addr_bytes, __float_as_int(v)));
}

// One sequence per 64-lane wave; alpha recursion as MFMA matvec in exp-space.
//
// Tag->k-slot assignment (used identically for A and B, so the hardware's
// internal k permutation cancels):  tau(c, r) = 32c + 16*(r>=4) + 4g + (r&3),
// g = lane>>4.  D layout (m89-verified): col = lane&15, row = 4*(lane>>4)+reg,
// so D tile i, reg r holds alpha[16i + 4g + r] -> exactly B's slot for that
// tag: D feeds next-step B with register moves only.  All 16 B columns are
// replicas of the single sequence.  Rescale: terminal row D4 = etstop.alpha
// gives a wave-uniform power-of-two scale via readfirstlane of its exponent
// (lagged one step; fp32 headroom absorbs the lag).
__global__ __launch_bounds__(64, 1) void crf_forward_mfma(
    const float* __restrict__ feats,        // (B,T,K)
    const float* __restrict__ transitions,  // (K,K), trans[i,j] = score j->i
    const int* __restrict__ lengths,        // (B,)
    float* __restrict__ fwd_out)            // (B,)
{
    const int b   = blockIdx.x;
    const int l   = threadIdx.x;
    const int row = l & 15;   // A row / D col
    const int g   = l >> 4;   // k-group

    // A fragments: A[i][c] slot r = exp(trans[16i+row][tau(c,r)])
    bf16x8 A00, A01, A10, A11, A20, A21, A30, A31, S0, S1;
#define MKA(Av, i, c) {                                                       \
    const float* p = transitions + (16*(i)+row)*Kk + 32*(c) + 4*g;            \
    float4 lo = *(const float4*)p; float4 hi = *(const float4*)(p + 16);      \
    Av[0]=f2bf(__expf(lo.x)); Av[1]=f2bf(__expf(lo.y));                       \
    Av[2]=f2bf(__expf(lo.z)); Av[3]=f2bf(__expf(lo.w));                       \
    Av[4]=f2bf(__expf(hi.x)); Av[5]=f2bf(__expf(hi.y));                       \
    Av[6]=f2bf(__expf(hi.z)); Av[7]=f2bf(__expf(hi.w)); }
    MKA(A00,0,0) MKA(A01,0,1) MKA(A10,1,0) MKA(A11,1,1)
    MKA(A20,2,0) MKA(A21,2,1) MKA(A30,3,0) MKA(A31,3,1)
#undef MKA
    // Terminal fragments: row 0 = exp(trans[STOP][tau]), rows 1..15 = 0
#define MKS(Av, c) {                                                          \
    const float* p = transitions + STOP_TAG*Kk + 32*(c) + 4*g;                \
    float4 lo = *(const float4*)p; float4 hi = *(const float4*)(p + 16);      \
    const bool z = (row == 0);                                                \
    Av[0]=z?f2bf(__expf(lo.x)):(short)0; Av[1]=z?f2bf(__expf(lo.y)):(short)0; \
    Av[2]=z?f2bf(__expf(lo.z)):(short)0; Av[3]=z?f2bf(__expf(lo.w)):(short)0; \
    Av[4]=z?f2bf(__expf(hi.x)):(short)0; Av[5]=z?f2bf(__expf(hi.y)):(short)0; \
    Av[6]=z?f2bf(__expf(hi.z)):(short)0; Av[7]=z?f2bf(__expf(hi.w)):(short)0; }
    MKS(S0,0) MKS(S1,1)
#undef MKS

    const int len = lengths[b];
    const float* fb = feats + (size_t)b * Tt * Kk + l;  // natural: lane = tag

    // emit prefetch, 6 deep (rows 0..511 always allocated)
    float e0=fb[0], e1=fb[1*Kk], e2=fb[2*Kk], e3=fb[3*Kk], e4=fb[4*Kk], e5=fb[5*Kk];

    // alpha0: 1 at START=62 -> c=1, g=3, slot 6
    bf16x8 B0 = {}; bf16x8 B1 = {};
    if (g == 3) B1[6] = (short)0x3F80;  // bf16(1.0)

    const int vb = g << 4;              // bpermute byte base: 4g floats * 4B
    const f32x4 zz = {0.f, 0.f, 0.f, 0.f};
    int ktot = 0, kcur = 0;
    float term = 1.0f;

    for (int t = 0; t < len; ++t) {
        ktot += kcur;
        // fac = e^emit * 2^-kcur, one transcendental per step (natural layout)
        const float fr = __builtin_amdgcn_exp2f(fmaf(e0, LOG2E, -(float)kcur));
        // rotate prefetch ring, issue load for t+6
        e0 = e1; e1 = e2; e2 = e3; e3 = e4; e4 = e5;
        const int tn = (t + 6 < Tt) ? t + 6 : Tt - 1;
        e5 = fb[tn * Kk];
        // redistribute fac into D layout: F[i][r] = fac[tag 16i+4g+r]
#define BP(i, r) bperm(vb + 64*(i) + 4*(r), fr)
        const float F00=BP(0,0), F01=BP(0,1), F02=BP(0,2), F03=BP(0,3);
        const float F10=BP(1,0), F11=BP(1,1), F12=BP(1,2), F13=BP(1,3);
        const float F20=BP(2,0), F21=BP(2,1), F22=BP(2,2), F23=BP(2,3);
        const float F30=BP(3,0), F31=BP(3,1), F32=BP(3,2), F33=BP(3,3);
#undef BP
        // D = eT @ alpha   (8 MFMAs, K accumulated)
        f32x4 d0 = __builtin_amdgcn_mfma_f32_16x16x32_bf16(A00, B0, zz, 0, 0, 0);
        d0 = __builtin_amdgcn_mfma_f32_16x16x32_bf16(A01, B1, d0, 0, 0, 0);
        f32x4 d1 = __builtin_amdgcn_mfma_f32_16x16x32_bf16(A10, B0, zz, 0, 0, 0);
        d1 = __builtin_amdgcn_mfma_f32_16x16x32_bf16(A11, B1, d1, 0, 0, 0);
        f32x4 d2 = __builtin_amdgcn_mfma_f32_16x16x32_bf16(A20, B0, zz, 0, 0, 0);
        d2 = __builtin_amdgcn_mfma_f32_16x16x32_bf16(A21, B1, d2, 0, 0, 0);
        f32x4 d3 = __builtin_amdgcn_mfma_f32_16x16x32_bf16(A30, B0, zz, 0, 0, 0);
        d3 = __builtin_amdgcn_mfma_f32_16x16x32_bf16(A31, B1, d3, 0, 0, 0);
        // alpha_new = D * fac -> bf16, packed straight into next B fragments
        bf16x8 N0, N1;
        N0[0]=f2bf(d0[0]*F00); N0[1]=f2bf(d0[1]*F01); N0[2]=f2bf(d0[2]*F02); N0[3]=f2bf(d0[3]*F03);
        N0[4]=f2bf(d1[0]*F10); N0[5]=f2bf(d1[1]*F11); N0[6]=f2bf(d1[2]*F12); N0[7]=f2bf(d1[3]*F13);
        N1[0]=f2bf(d2[0]*F20); N1[1]=f2bf(d2[1]*F21); N1[2]=f2bf(d2[2]*F22); N1[3]=f2bf(d2[3]*F23);
        N1[4]=f2bf(d3[0]*F30); N1[5]=f2bf(d3[1]*F31); N1[6]=f2bf(d3[2]*F32); N1[7]=f2bf(d3[3]*F33);
        B0 = N0; B1 = N1;
        // terminal row: d4[0] (lane 0) = etstop . alpha_{t+1}  (scaled 2^-ktot')
        f32x4 d4 = __builtin_amdgcn_mfma_f32_16x16x32_bf16(S0, B0, zz, 0, 0, 0);
        d4 = __builtin_amdgcn_mfma_f32_16x16x32_bf16(S1, B1, d4, 0, 0, 0);
        const unsigned tb_ = (unsigned)__builtin_amdgcn_readfirstlane(__float_as_int(d4[0]));
        term = __uint_as_float(tb_);
        kcur = (int)((tb_ >> 23) & 255) - 127;  // next step's scale (lagged)
    }

    if (l == 0) fwd_out[b] = (float)ktot * LN2F + logf(term);
}

// Gold path score: fully parallel over t (lane-strided).
__global__ __launch_bounds__(64) void crf_gold_kernel(
    const float* __restrict__ feats,
    const float* __restrict__ transitions,
    const int* __restrict__ tags,     // (B,T)
    const int* __restrict__ lengths,  // (B,)
    float* __restrict__ gold_out)     // (B,)
{
    const int b = blockIdx.x;
    const int lane = threadIdx.x;
    const int len = lengths[b];
    const int* tb = tags + b * Tt;
    const float* fb = feats + (size_t)b * Tt * Kk;

    float acc = 0.f;
    for (int t = lane; t < len; t += 64) {
        const int tg = tb[t];
        const int prev = (t == 0) ? START_TAG : tb[t - 1];
        acc += transitions[tg * Kk + prev];  // score prev -> tg
        acc += fb[t * Kk + tg];              // emission
    }
    if (lane == 0) acc += transitions[STOP_TAG * Kk + tb[len - 1]];  // last -> STOP
#pragma unroll
    for (int off = 32; off >= 1; off >>= 1) acc += __shfl_xor(acc, off, 64);
    if (lane == 0) gold_out[b] = acc;
}

__global__ __launch_bounds__(512) void crf_reduce_kernel(
    const float* __restrict__ fwd, const float* __restrict__ gold,
    float* __restrict__ out)
{
    const int i = threadIdx.x;  // 0..511
    float v = fwd[i] - gold[i];
#pragma unroll
    for (int off = 32; off >= 1; off >>= 1) v += __shfl_xor(v, off, 64);
    __shared__ float ws[8];
    if ((i & 63) == 0) ws[i >> 6] = v;
    __syncthreads();
    if (i < 8) {
        float s = ws[i];
#pragma unroll
        for (int off = 4; off >= 1; off >>= 1) s += __shfl_xor(s, off, 8);
        if (i == 0) out[0] = s * (1.0f / (float)Bb);
    }
}

extern "C" void kernel_launch(void* const* d_in, const int* in_sizes, int n_in,
                              void* d_out, int out_size, void* d_ws, size_t ws_size,
                              hipStream_t stream) {
    const float* feats = (const float*)d_in[0];
    const float* trans = (const float*)d_in[1];
    const int* tags = (const int*)d_in[2];
    const int* lengths = (const int*)d_in[3];
    float* out = (float*)d_out;
    float* fwd = (float*)d_ws;
    float* gold = fwd + Bb;

    crf_gold_kernel<<<Bb, 64, 0, stream>>>(feats, trans, tags, lengths, gold);
    crf_forward_mfma<<<Bb, 64, 0, stream>>>(feats, trans, lengths, fwd);
    crf_reduce_kernel<<<1, 512, 0, stream>>>(fwd, gold, out);
}

// Round 5
// 97.510 us; speedup vs baseline: 2.1965x; 2.1965x over previous
//
#include <hip/hip_runtime.h>
#include <hip/hip_bf16.h>

#define Bb 512
#define Tt 512
#define Kk 64
#define START_TAG 62
#define STOP_TAG 63
#define LN2F 0.69314718055994530942f
#define LOG2E 1.44269504088896340736f

typedef __attribute__((ext_vector_type(8))) short bf16x8;  // 8 bf16 in 4 VGPRs
typedef __attribute__((ext_vector_type(4))) float f32x4;   // MFMA C/D

__device__ inline short f2bf(float x) {
    __hip_bfloat16 h = __float2bfloat16(x);
    short s; __builtin_memcpy(&s, &h, 2); return s;
}
// pack 2 f32 -> 2 bf16 (lo = first arg) in ONE instruction; register-only asm,
// schedulable, replaces ~5-instr software RNE per value on the serial chain.
__device__ inline unsigned cvtpk(float lo, float hi) {
    unsigned r;
    asm("v_cvt_pk_bf16_f32 %0, %1, %2" : "=v"(r) : "v"(lo), "v"(hi));
    return r;
}

// One sequence per 64-lane wave; alpha recursion as MFMA matvec in exp-space.
// Round-4 layout (HW-verified, absmax 0.0): tag tau(c,r)=32c+16*(r>=4)+4g+(r&3)
// on both A and B sides; D tile i reg r = tag 16i+4g+r -> D feeds next B with
// register moves only. This round strips the serial chain: no terminal MFMA in
// the loop, emit factors decoupled from the recursion (prefetched via LDS
// write/read-broadcast one step ahead), rescale folded into F off-path,
// cvt_pk for bf16 packing.
__global__ __launch_bounds__(64, 1) void crf_forward_mfma(
    const float* __restrict__ feats,        // (B,T,K)
    const float* __restrict__ transitions,  // (K,K), trans[i,j] = score j->i
    const int* __restrict__ lengths,        // (B,)
    float* __restrict__ fwd_out)            // (B,)
{
    const int b   = blockIdx.x;
    const int l   = threadIdx.x;
    const int row = l & 15;   // A row / D col
    const int g   = l >> 4;   // k-group

    // fr banks: fr(t) in natural layout (lane = tag), double-buffered.
    __shared__ __align__(16) float frl[2][Kk];

    // A fragments: A[i][c] slot r = exp(trans[16i+row][tau(c,r)])
    bf16x8 A00, A01, A10, A11, A20, A21, A30, A31, S0, S1;
#define MKA(Av, i, c) {                                                       \
    const float* p = transitions + (16*(i)+row)*Kk + 32*(c) + 4*g;            \
    float4 lo = *(const float4*)p; float4 hi = *(const float4*)(p + 16);      \
    Av[0]=f2bf(__expf(lo.x)); Av[1]=f2bf(__expf(lo.y));                       \
    Av[2]=f2bf(__expf(lo.z)); Av[3]=f2bf(__expf(lo.w));                       \
    Av[4]=f2bf(__expf(hi.x)); Av[5]=f2bf(__expf(hi.y));                       \
    Av[6]=f2bf(__expf(hi.z)); Av[7]=f2bf(__expf(hi.w)); }
    MKA(A00,0,0) MKA(A01,0,1) MKA(A10,1,0) MKA(A11,1,1)
    MKA(A20,2,0) MKA(A21,2,1) MKA(A30,3,0) MKA(A31,3,1)
#undef MKA
    // Terminal fragments: row 0 = exp(trans[STOP][tau]), rows 1..15 = 0
#define MKS(Av, c) {                                                          \
    const float* p = transitions + STOP_TAG*Kk + 32*(c) + 4*g;                \
    float4 lo = *(const float4*)p; float4 hi = *(const float4*)(p + 16);      \
    const bool z = (row == 0);                                                \
    Av[0]=z?f2bf(__expf(lo.x)):(short)0; Av[1]=z?f2bf(__expf(lo.y)):(short)0; \
    Av[2]=z?f2bf(__expf(lo.z)):(short)0; Av[3]=z?f2bf(__expf(lo.w)):(short)0; \
    Av[4]=z?f2bf(__expf(hi.x)):(short)0; Av[5]=z?f2bf(__expf(hi.y)):(short)0; \
    Av[6]=z?f2bf(__expf(hi.z)):(short)0; Av[7]=z?f2bf(__expf(hi.w)):(short)0; }
    MKS(S0,0) MKS(S1,1)
#undef MKS

    const int len = lengths[b];
    const float* fb = feats + (size_t)b * Tt * Kk + l;  // natural: lane = tag

    // alpha0: 1 at START=62 -> B1 slot 6, g=3
    bf16x8 B0 = {}; bf16x8 B1 = {};
    if (g == 3) B1[6] = (short)0x3F80;  // bf16(1.0)

    const float* bank0 = &frl[0][4 * g];
    const float* bank1 = &frl[1][4 * g];

    // ---- prologue: FA=F(0), FB=F(1); bank0=fr(2), bank1=fr(3) ----
    const float fr0_ = __builtin_amdgcn_exp2f(fb[0]      * LOG2E);
    const float fr1_ = __builtin_amdgcn_exp2f(fb[Kk]     * LOG2E);
    const float fr2_ = __builtin_amdgcn_exp2f(fb[2 * Kk] * LOG2E);
    const float fr3_ = __builtin_amdgcn_exp2f(fb[3 * Kk] * LOG2E);
    f32x4 FA0, FA1, FA2, FA3, FB0, FB1, FB2, FB3;
    frl[0][l] = fr0_;
    __builtin_amdgcn_wave_barrier();
    FA0 = *(const f32x4*)(bank0);      FA1 = *(const f32x4*)(bank0 + 16);
    FA2 = *(const f32x4*)(bank0 + 32); FA3 = *(const f32x4*)(bank0 + 48);
    __builtin_amdgcn_wave_barrier();
    frl[0][l] = fr2_;                  // after FA reads (same-wave DS FIFO)
    frl[1][l] = fr1_;
    __builtin_amdgcn_wave_barrier();
    FB0 = *(const f32x4*)(bank1);      FB1 = *(const f32x4*)(bank1 + 16);
    FB2 = *(const f32x4*)(bank1 + 32); FB3 = *(const f32x4*)(bank1 + 48);
    __builtin_amdgcn_wave_barrier();
    frl[1][l] = fr3_;

    // emit ring: er0..er3 = rows t+4..t+7
    float er0 = fb[4 * Kk], er1 = fb[5 * Kk], er2 = fb[6 * Kk], er3 = fb[7 * Kk];

    const f32x4 zz = {0.f, 0.f, 0.f, 0.f};
    int ktot = 0;
    float probeA, probeB;

#define MFMA16(Aa, Bx, Cc) __builtin_amdgcn_mfma_f32_16x16x32_bf16(Aa, Bx, Cc, 0, 0, 0)

    // one recursion step: d = eT@alpha (2-chained MFMAs x4), N = d*F, pack bf16
#define STEP(F0_, F1_, F2_, F3_, PR) {                                        \
    f32x4 d0 = MFMA16(A00, B0, zz); d0 = MFMA16(A01, B1, d0);                 \
    f32x4 d1 = MFMA16(A10, B0, zz); d1 = MFMA16(A11, B1, d1);                 \
    f32x4 d2 = MFMA16(A20, B0, zz); d2 = MFMA16(A21, B1, d2);                 \
    f32x4 d3 = MFMA16(A30, B0, zz); d3 = MFMA16(A31, B1, d3);                 \
    f32x4 m0 = d0 * F0_, m1 = d1 * F1_, m2 = d2 * F2_, m3 = d3 * F3_;         \
    PR = m0[0];                                                               \
    union { unsigned u[4]; bf16x8 v; } nb0, nb1;                              \
    nb0.u[0] = cvtpk(m0[0], m0[1]); nb0.u[1] = cvtpk(m0[2], m0[3]);           \
    nb0.u[2] = cvtpk(m1[0], m1[1]); nb0.u[3] = cvtpk(m1[2], m1[3]);           \
    nb1.u[0] = cvtpk(m2[0], m2[1]); nb1.u[1] = cvtpk(m2[2], m2[3]);           \
    nb1.u[2] = cvtpk(m3[0], m3[1]); nb1.u[3] = cvtpk(m3[2], m3[3]);           \
    B0 = nb0.v; B1 = nb1.v; }

    int t = 0;
    for (; t + 1 < len; t += 2) {
        // ---- slot A (step t): prefetch F(t+2); write fr(t+4) ----
        const float frA = __builtin_amdgcn_exp2f(er0 * LOG2E);
        f32x4 NA0 = *(const f32x4*)(bank0);      f32x4 NA1 = *(const f32x4*)(bank0 + 16);
        f32x4 NA2 = *(const f32x4*)(bank0 + 32); f32x4 NA3 = *(const f32x4*)(bank0 + 48);
        __builtin_amdgcn_wave_barrier();
        frl[0][l] = frA;                // after NA reads (DS FIFO: no clobber)
        STEP(FA0, FA1, FA2, FA3, probeA)
        // ---- slot B (step t+1): prefetch F(t+3); write fr(t+5) ----
        const float frB = __builtin_amdgcn_exp2f(er1 * LOG2E);
        f32x4 NB0 = *(const f32x4*)(bank1);      f32x4 NB1 = *(const f32x4*)(bank1 + 16);
        f32x4 NB2 = *(const f32x4*)(bank1 + 32); f32x4 NB3 = *(const f32x4*)(bank1 + 48);
        __builtin_amdgcn_wave_barrier();
        frl[1][l] = frB;
        STEP(FB0, FB1, FB2, FB3, probeB)
        // ---- rescale (off critical path): fold 2^-k into F(t+2) ----
        // probeB = alpha_{t+2}[tag0] > 0 (valid from step 1 on); any
        // wave-uniform pow2 works, fp32 headroom >> 2-step growth.
        const unsigned pb =
            (unsigned)__builtin_amdgcn_readfirstlane(__float_as_int(probeB));
        const int k = (int)((pb >> 23) & 255) - 127;
        ktot += k;
        const float s = __uint_as_float((unsigned)(127 - k) << 23);
        const f32x4 sv = {s, s, s, s};
        FA0 = NA0 * sv; FA1 = NA1 * sv; FA2 = NA2 * sv; FA3 = NA3 * sv;
        FB0 = NB0; FB1 = NB1; FB2 = NB2; FB3 = NB3;
        // ---- emit ring: load rows t+8, t+9 (clamped; rows always exist) ----
        er0 = er2; er1 = er3;
        const int r0 = (t + 8 < Tt) ? t + 8 : Tt - 1;
        const int r1 = (t + 9 < Tt) ? t + 9 : Tt - 1;
        er2 = fb[r0 * Kk]; er3 = fb[r1 * Kk];
    }

    // tail (len odd): one step with FA = F(t)
    if (t < len) {
        STEP(FA0, FA1, FA2, FA3, probeA)
        (void)probeA;
    }

    // terminal: d4 row0 = etstop . alpha (current scale 2^-ktot)
    f32x4 d4 = MFMA16(S0, B0, zz); d4 = MFMA16(S1, B1, d4);
    const float term = __uint_as_float(
        (unsigned)__builtin_amdgcn_readfirstlane(__float_as_int(d4[0])));
    if (l == 0) fwd_out[b] = (float)ktot * LN2F + logf(term);
#undef STEP
#undef MFMA16
}

// Gold path score: fully parallel over t (lane-strided).
__global__ __launch_bounds__(64) void crf_gold_kernel(
    const float* __restrict__ feats,
    const float* __restrict__ transitions,
    const int* __restrict__ tags,     // (B,T)
    const int* __restrict__ lengths,  // (B,)
    float* __restrict__ gold_out)     // (B,)
{
    const int b = blockIdx.x;
    const int lane = threadIdx.x;
    const int len = lengths[b];
    const int* tb = tags + b * Tt;
    const float* fb = feats + (size_t)b * Tt * Kk;

    float acc = 0.f;
    for (int t = lane; t < len; t += 64) {
        const int tg = tb[t];
        const int prev = (t == 0) ? START_TAG : tb[t - 1];
        acc += transitions[tg * Kk + prev];  // score prev -> tg
        acc += fb[t * Kk + tg];              // emission
    }
    if (lane == 0) acc += transitions[STOP_TAG * Kk + tb[len - 1]];  // last -> STOP
#pragma unroll
    for (int off = 32; off >= 1; off >>= 1) acc += __shfl_xor(acc, off, 64);
    if (lane == 0) gold_out[b] = acc;
}

__global__ __launch_bounds__(512) void crf_reduce_kernel(
    const float* __restrict__ fwd, const float* __restrict__ gold,
    float* __restrict__ out)
{
    const int i = threadIdx.x;  // 0..511
    float v = fwd[i] - gold[i];
#pragma unroll
    for (int off = 32; off >= 1; off >>= 1) v += __shfl_xor(v, off, 64);
    __shared__ float ws[8];
    if ((i & 63) == 0) ws[i >> 6] = v;
    __syncthreads();
    if (i < 8) {
        float s = ws[i];
#pragma unroll
        for (int off = 4; off >= 1; off >>= 1) s += __shfl_xor(s, off, 8);
        if (i == 0) out[0] = s * (1.0f / (float)Bb);
    }
}

extern "C" void kernel_launch(void* const* d_in, const int* in_sizes, int n_in,
                              void* d_out, int out_size, void* d_ws, size_t ws_size,
                              hipStream_t stream) {
    const float* feats = (const float*)d_in[0];
    const float* trans = (const float*)d_in[1];
    const int* tags = (const int*)d_in[2];
    const int* lengths = (const int*)d_in[3];
    float* out = (float*)d_out;
    float* fwd = (float*)d_ws;
    float* gold = fwd + Bb;

    crf_gold_kernel<<<Bb, 64, 0, stream>>>(feats, trans, tags, lengths, gold);
    crf_forward_mfma<<<Bb, 64, 0, stream>>>(feats, trans, lengths, fwd);
    crf_reduce_kernel<<<1, 512, 0, stream>>>(fwd, gold, out);
}